// Round 4
// baseline (343.007 us; speedup 1.0000x reference)
//
#include <hip/hip_runtime.h>

#define B_ 16
#define S_ 20
#define L_ 64
#define T_ 1280
#define H_ 768
#define NITEMS 50000
#define TEMP 0.05f
#define EPSN 1e-8f

#define BK 32
#define NKT (H_ / BK)  // 24
#define BM1 80         // per-block A rows = 4 sessions
#define BN1 64         // per-block items
#define NCHUNK 782     // ceil(50000/64)
#define PERX 98        // n-chunks per XCD (8*98=784 >= 782)
#define GRID1 (8 * 4 * PERX)  // 3136 one-wave blocks

typedef __attribute__((ext_vector_type(8))) short short8;
typedef __attribute__((ext_vector_type(4))) float f32x4;

// float -> bf16 (round-to-nearest-even)
__device__ __forceinline__ unsigned short f2bf(float f) {
    unsigned int u = __float_as_uint(f);
    u = u + 0x7FFFu + ((u >> 16) & 1u);
    return (unsigned short)(u >> 16);
}

// async global->LDS, 16B per lane. LDS dest must be wave-uniform base + lane*16.
typedef __attribute__((address_space(3))) void lds_void;
typedef const __attribute__((address_space(1))) void gbl_void;
__device__ __forceinline__ void load_lds16(const void* g, void* l) {
    __builtin_amdgcn_global_load_lds((gbl_void*)g, (lds_void*)l, 16, 0, 0);
}

// ---------------------------------------------------------------------------
// Kernel 1: per-(b,s) nan-mean pool, normalize, fold 1/(pn*TEMP), write bf16.
// Output slot-swizzle: logical 16B-slot q of row r stored at q ^ ((r>>1)&3)
// within each 32-col chunk (verified conflict-free in rounds 2-3).
// ---------------------------------------------------------------------------
__global__ __launch_bounds__(384) void pool_kernel(const float* __restrict__ hidden,
                                                   const int* __restrict__ pos,
                                                   unsigned short* __restrict__ A,
                                                   int* __restrict__ valid) {
    const int row = blockIdx.x;  // 0..319
    const int b = row / S_, s = row % S_;
    const int tid = threadIdx.x;  // 0..383; thread owns cols 2*tid, 2*tid+1

    __shared__ float wgt[L_];
    __shared__ int cntS;
    __shared__ float red[6];

    const int* pbase = pos + b * T_ + s * L_;
    if (tid < L_) {  // exactly wave 0
        const int match = (pbase[tid] == s + 1) ? 1 : 0;
        unsigned long long bal = __ballot(match);
        wgt[tid] = match ? 1.0f : 0.0f;
        if (tid == 0) cntS = (int)__popcll(bal);
    }
    __syncthreads();

    const int cnt = cntS;
    const float inv = 1.0f / (float)(cnt > 0 ? cnt : 1);
    const float* hbase = hidden + ((size_t)b * T_ + (size_t)s * L_) * H_ + tid * 2;

    float a0 = 0.f, a1 = 0.f;
#pragma unroll 8
    for (int t = 0; t < L_; ++t) {
        const float w = wgt[t];
        const float2 v = *reinterpret_cast<const float2*>(hbase + (size_t)t * H_);
        a0 += w * v.x; a1 += w * v.y;
    }
    a0 *= inv; a1 *= inv;

    // sum of squares over 768 cols (6 waves)
    float ss = a0 * a0 + a1 * a1;
#pragma unroll
    for (int off = 32; off; off >>= 1) ss += __shfl_xor(ss, off, 64);
    const int wave = tid >> 6, lane = tid & 63;
    if (lane == 0) red[wave] = ss;
    __syncthreads();
    const float tot = red[0] + red[1] + red[2] + red[3] + red[4] + red[5];
    const float scale = 1.0f / (fmaxf(sqrtf(tot), EPSN) * TEMP);

    // swizzled store: c0 = 2*tid; chunk = c0>>5; logical slot (c0>>3)&3
    const int chunk = tid >> 4;
    const int cSlot = (tid >> 2) & 3;
    const int phys = cSlot ^ ((row >> 1) & 3);
    unsigned short r0 = f2bf(a0 * scale);
    unsigned short r1 = f2bf(a1 * scale);
    unsigned int pk = (unsigned int)r0 | ((unsigned int)r1 << 16);
    *reinterpret_cast<unsigned int*>(A + (size_t)row * H_ + chunk * 32 + phys * 8 +
                                     ((tid * 2) & 7)) = pk;
    if (tid == 0) valid[row] = (cnt > 0) ? 1 : 0;
}

// ---------------------------------------------------------------------------
// Kernel 2: BARRIER-FREE one-wave GEMM blocks (80x64 tile each).
// R1-R3 evidence: the 4-wave barrier-coupled 2-phase loop has a ~3.5-6k cy
// fixed sync tax per K-iter immune to schedule/occupancy (regime-gate: T4
// null on 2-phase). Single-wave blocks remove s_barrier entirely: producer
// and consumer are the same wave, so one counted `s_waitcnt vmcnt(13)` per
// iter is the ONLY sync, and 6 independent waves/CU hide each other.
//  - A: 5 gload_lds issues/iter (bf16 ws slice, pre-swizzled rows).
//  - B: 8 gload_lds issues/iter (fp32, source-column pre-swizzled so the
//    linear DMA dest yields conflict-free swizzled reads; rule 21).
//  - en: per-lane fp32 accumulation from the staged B fragments; cross-quad
//    shfl at the end lands inv_en exactly in the epilogue's lane layout.
//  - XCD pinning: the 4 m-sibling blocks sharing an emb range get the same
//    blockIdx%8 -> same XCD L2 (no cross-XCD B amplification).
// LDS 26KB -> 6 blocks/CU. ~140 VGPR (acc 80 + ptrs/frags).
// ---------------------------------------------------------------------------
__global__ __launch_bounds__(64) void gemm_kernel(const float* __restrict__ emb,
                                                  const unsigned short* __restrict__ A,
                                                  const int* __restrict__ valid,
                                                  float* __restrict__ out) {
    const int i = blockIdx.x;
    const int xcd = i & 7;
    const int k = i >> 3;
    const int m = k & 3;                 // A row-slice: rows 80m..80m+79
    const int nc = xcd * PERX + (k >> 2);
    if (nc >= NCHUNK) return;            // 8 idle pad blocks
    const int n0 = nc * BN1;

    const int lane = threadIdx.x;        // 0..63
    const int quad = lane >> 4, lq = lane & 15;

    __shared__ alignas(16) short As[2][BM1 * BK];  // 2 x 5 KB bf16 (swizzled rows)
    __shared__ alignas(16) float Bs[2][BN1 * BK];  // 2 x 8 KB fp32 (swizzled slots)
    __shared__ int sMask[4];

    // session validity masks for this block's 4 sessions (lanes 0..3)
    if (lane < 4) {
        int mm = 0;
        for (int s = 0; s < S_; ++s) mm |= (valid[(m * 4 + lane) * S_ + s] ? 1 : 0) << s;
        sMask[lane] = mm;
    }

    // --- staging geometry ---
    // A: issue i0 covers rows m*80 + i0*16 + (lane>>2), 16B-slot lane&3 (ws
    // is row-pre-swizzled so the DMA copy is verbatim).
    const unsigned short* aSrc = A + (size_t)(m * BM1 + (lane >> 2)) * H_ + (lane & 3) * 8;
    // B: issue i1 covers dest row r = i1*8 + (lane>>3), dest 16B-slot d = lane&7.
    // Swizzle: phys slot d holds logical slot d^(r&7); r&7 == lane>>3 for all
    // issues, so the source column is issue-invariant.
    const int bCol = (((lane & 7) ^ (lane >> 3)) * 4);
    const float* bPtr[8];
#pragma unroll
    for (int i1 = 0; i1 < 8; ++i1) {
        int r = n0 + i1 * 8 + (lane >> 3);
        if (r > NITEMS - 1) r = NITEMS - 1;  // clamp: computed, never stored
        bPtr[i1] = emb + (size_t)r * H_ + bCol;
    }

#define STAGE(bufidx, k0)                                                              \
    do {                                                                               \
        _Pragma("unroll") for (int i0 = 0; i0 < 5; ++i0)                               \
            load_lds16(aSrc + (k0) + i0 * 16 * H_,                                     \
                       (char*)(&As[bufidx][0]) + lane * 16 + i0 * 1024);               \
        _Pragma("unroll") for (int i1 = 0; i1 < 8; ++i1)                               \
            load_lds16(bPtr[i1] + (k0), (char*)(&Bs[bufidx][0]) + lane * 16 + i1 * 1024); \
    } while (0)

    // prologue: stage tile 0 into buffer 0
    STAGE(0, 0);

    f32x4 acc[5][4];
#pragma unroll
    for (int a = 0; a < 5; ++a)
#pragma unroll
        for (int b = 0; b < 4; ++b) acc[a][b] = (f32x4)0.f;
    float enAcc[4] = {0.f, 0.f, 0.f, 0.f};

    const int fswzA = (lq >> 1) & 3;  // A frag slot swizzle (rows: (r>>1)&3 == (lq>>1)&3)
    const int swzB = lq & 7;          // B frag slot swizzle (rows: r&7 == lq&7)

    for (int kt = 0; kt < NKT; ++kt) {
        const int buf = kt & 1;
        // issue next tile's 13 loads into the other buffer (stay in flight)
        if (kt + 1 < NKT) {
            const int k0 = (kt + 1) * BK;
            STAGE(buf ^ 1, k0);
            // wait tile kt's 13 loads only (13 newer remain outstanding)
            asm volatile("s_waitcnt vmcnt(13)" ::: "memory");
        } else {
            asm volatile("s_waitcnt vmcnt(0)" ::: "memory");
        }

        // B fragments: fp32 swizzled reads + en partials + cvt -> bf16
        short8 bF[4];
#pragma unroll
        for (int nf = 0; nf < 4; ++nf) {
            const int r = nf * 16 + lq;
            const f32x4 x = *reinterpret_cast<const f32x4*>(
                &Bs[buf][r * BK + (((quad * 2) ^ swzB) * 4)]);
            const f32x4 y = *reinterpret_cast<const f32x4*>(
                &Bs[buf][r * BK + (((quad * 2 + 1) ^ swzB) * 4)]);
            enAcc[nf] += x[0] * x[0] + x[1] * x[1] + x[2] * x[2] + x[3] * x[3] +
                         y[0] * y[0] + y[1] * y[1] + y[2] * y[2] + y[3] * y[3];
            short8 f;
            f[0] = (short)f2bf(x[0]); f[1] = (short)f2bf(x[1]);
            f[2] = (short)f2bf(x[2]); f[3] = (short)f2bf(x[3]);
            f[4] = (short)f2bf(y[0]); f[5] = (short)f2bf(y[1]);
            f[6] = (short)f2bf(y[2]); f[7] = (short)f2bf(y[3]);
            bF[nf] = f;
        }

        // A fragments + MFMA: 5 m-frags x 4 n-frags
#pragma unroll
        for (int mf = 0; mf < 5; ++mf) {
            const short8 aF = *reinterpret_cast<const short8*>(
                &As[buf][(mf * 16 + lq) * BK + ((quad ^ fswzA) * 8)]);
#pragma unroll
            for (int nf = 0; nf < 4; ++nf)
                acc[mf][nf] =
                    __builtin_amdgcn_mfma_f32_16x16x32_bf16(aF, bF[nf], acc[mf][nf], 0, 0, 0);
        }
    }
#undef STAGE

    // finalize en: sum partial squares across the 4 quads (lanes share lq)
    float inv_en[4];
#pragma unroll
    for (int nf = 0; nf < 4; ++nf) {
        float e = enAcc[nf];
        e += __shfl_xor(e, 16, 64);
        e += __shfl_xor(e, 32, 64);
        inv_en[nf] = 1.0f / fmaxf(sqrtf(e), EPSN);
    }

    // epilogue: sessions 4m..4m+3 live at local rows bl*20..bl*20+19.
    // C/D layout: col = lane&15 (n), row = quad*4+e (m).
#pragma unroll
    for (int nf = 0; nf < 4; ++nf) {
        const int n = n0 + nf * 16 + lq;
#pragma unroll
        for (int bl = 0; bl < 4; ++bl) {
            const int msk = sMask[bl];
            const int rLo = bl * S_;
            float lm = -__builtin_inff();
            const int mfLo = rLo >> 4;
            const int mfHi = (rLo + S_ - 1) >> 4;
#pragma unroll
            for (int mf = mfLo; mf <= mfHi; ++mf)
#pragma unroll
                for (int e = 0; e < 4; ++e) {
                    const int r = mf * 16 + quad * 4 + e;
                    const unsigned off = (unsigned)(r - rLo);
                    const bool ok = (off < (unsigned)S_) && ((msk >> off) & 1);
                    lm = ok ? fmaxf(lm, acc[mf][nf][e]) : lm;
                }
            lm = fmaxf(lm, __shfl_xor(lm, 16, 64));
            lm = fmaxf(lm, __shfl_xor(lm, 32, 64));
            if (quad == 0 && n < NITEMS)
                out[(size_t)(m * 4 + bl) * NITEMS + n] = lm * inv_en[nf];
        }
    }
}

extern "C" void kernel_launch(void* const* d_in, const int* in_sizes, int n_in,
                              void* d_out, int out_size, void* d_ws, size_t ws_size,
                              hipStream_t stream) {
    const float* hidden = (const float*)d_in[0];   // [16,1280,768] f32
    const float* emb    = (const float*)d_in[1];   // [50000,768] f32
    const int*   pos    = (const int*)d_in[3];     // [16,1280] i32
    float* out = (float*)d_out;                    // [16,50000] f32

    unsigned short* Abf = (unsigned short*)d_ws;               // 320*768 bf16 (swizzled)
    int* valid = (int*)((char*)d_ws + (size_t)320 * 768 * 2);  // 320 ints

    pool_kernel<<<dim3(320), dim3(384), 0, stream>>>(hidden, pos, Abf, valid);
    gemm_kernel<<<dim3(GRID1), dim3(64), 0, stream>>>(emb, Abf, valid, out);
}